// Round 1
// baseline (679.381 us; speedup 1.0000x reference)
//
#include <hip/hip_runtime.h>

// Quantized vector-matrix multiply: out[n] = sum_k (x[k]-Xzp)*Xs * (y[k,n]-Yzp)*Ys
// Exact-integer reformulation:
//   out[n] = Xs*Ys * ( sum_k xs[k]*y[k,n] - Yzp * sum_k xs[k] ),  xs = x - Xzp
// Max |acc| ~ 1.6e8 -> fits int32 exactly.

constexpr int K = 8192;
constexpr int N = 16384;
constexpr float X_SCALE = 0.0215f;
constexpr int   X_ZP    = -25;
constexpr float Y_SCALE = 0.0176f;
constexpr int   Y_ZP    = 18;

constexpr int BLOCK = 256;
constexpr int VEC   = 4;                       // int4 loads: 16 B/lane
constexpr int COLS_PER_BLOCK = BLOCK * VEC;    // 1024
constexpr int NBLK_N = N / COLS_PER_BLOCK;     // 16
constexpr int SPLIT_K = 64;                    // 1024 blocks total -> 16 waves/CU
constexpr int KCHUNK = K / SPLIT_K;            // 128

__global__ void zero_out_kernel(float* __restrict__ out) {
    int i = blockIdx.x * blockDim.x + threadIdx.x;
    if (i < N) out[i] = 0.0f;
}

__global__ __launch_bounds__(BLOCK) void qgemv_kernel(const int* __restrict__ x,
                                                      const int* __restrict__ y,
                                                      float* __restrict__ out) {
    __shared__ int xs[KCHUNK];

    const int nb = blockIdx.x % NBLK_N;
    const int kc = blockIdx.x / NBLK_N;
    const int k0 = kc * KCHUNK;

    // Stage x chunk into LDS, pre-shifted by zero point.
    for (int i = threadIdx.x; i < KCHUNK; i += BLOCK)
        xs[i] = x[k0 + i] - X_ZP;
    __syncthreads();

    const int col = nb * COLS_PER_BLOCK + threadIdx.x * VEC;
    const int4* yv = (const int4*)(y + (size_t)k0 * N + col);
    const size_t stride4 = N / VEC;  // int4 elements per row

    int acc0 = 0, acc1 = 0, acc2 = 0, acc3 = 0;
    int sx = 0;

#pragma unroll 8
    for (int k = 0; k < KCHUNK; ++k) {
        int4 v = yv[(size_t)k * stride4];
        int a = xs[k];
        sx   += a;
        acc0 += a * v.x;
        acc1 += a * v.y;
        acc2 += a * v.z;
        acc3 += a * v.w;
    }

    const float sxy = X_SCALE * Y_SCALE;
    const int corr = Y_ZP * sx;
    atomicAdd(&out[col + 0], sxy * (float)(acc0 - corr));
    atomicAdd(&out[col + 1], sxy * (float)(acc1 - corr));
    atomicAdd(&out[col + 2], sxy * (float)(acc2 - corr));
    atomicAdd(&out[col + 3], sxy * (float)(acc3 - corr));
}

extern "C" void kernel_launch(void* const* d_in, const int* in_sizes, int n_in,
                              void* d_out, int out_size, void* d_ws, size_t ws_size,
                              hipStream_t stream) {
    const int* x = (const int*)d_in[0];
    const int* y = (const int*)d_in[1];
    float* out = (float*)d_out;

    zero_out_kernel<<<(N + 255) / 256, 256, 0, stream>>>(out);
    qgemv_kernel<<<NBLK_N * SPLIT_K, BLOCK, 0, stream>>>(x, y, out);
}

// Round 3
// 673.876 us; speedup vs baseline: 1.0082x; 1.0082x over previous
//
#include <hip/hip_runtime.h>

// Quantized vector-matrix multiply: out[n] = sum_k (x[k]-Xzp)*Xs * (y[k,n]-Yzp)*Ys
// Exact-integer reformulation:
//   out[n] = Xs*Ys * sum_k xs[k]*(y[k,n]-Yzp),  xs = x - X_ZP
//          = Xs*Ys * ( sum_k xs[k]*y[k,n] - Yzp*sum_k xs[k] )
// Max |acc| ~ 8192*152*127 ~ 1.6e8 -> fits int32 exactly (more accurate than fp32 ref).
//
// Structure: split-K GEMV. Each block computes a [KCHUNK x 1024-col] partial and
// stores it (with its chunk's zero-point correction already applied) as int32 into
// d_ws — plain stores, no atomics, no output pre-zeroing. A second tiny kernel
// sums the SPLIT_K partials per column (4 MiB traffic) and applies the fp scale.

constexpr int K = 8192;
constexpr int N = 16384;
constexpr float X_SCALE = 0.0215f;
constexpr int   X_ZP    = -25;
constexpr float Y_SCALE = 0.0176f;
constexpr int   Y_ZP    = 18;

constexpr int BLOCK = 256;
constexpr int VEC   = 4;                       // 16 B/lane loads (coalescing sweet spot)
constexpr int COLS_PER_BLOCK = BLOCK * VEC;    // 1024
constexpr int NBLK_N = N / COLS_PER_BLOCK;     // 16
constexpr int SPLIT_K = 64;                    // 1024 blocks -> 4 blocks/CU, 16 waves/CU
constexpr int KCHUNK = K / SPLIT_K;            // 128
constexpr int N4 = N / 4;                      // vec4 elements per row

// Native clang vector type: __builtin_nontemporal_load requires it (HIP_vector_type int4 is invalid).
typedef int ivec4 __attribute__((ext_vector_type(4)));

__global__ __launch_bounds__(BLOCK, 4) void qgemv_partial(const int* __restrict__ x,
                                                          const ivec4* __restrict__ y,
                                                          ivec4* __restrict__ ws) {
    __shared__ int xs[KCHUNK];

    const int nb = blockIdx.x % NBLK_N;
    const int kc = blockIdx.x / NBLK_N;
    const int k0 = kc * KCHUNK;

    // Stage x chunk into LDS, pre-shifted by zero point (broadcast reads later: conflict-free).
    for (int i = threadIdx.x; i < KCHUNK; i += BLOCK)
        xs[i] = x[k0 + i] - X_ZP;
    __syncthreads();

    const int col4 = nb * (COLS_PER_BLOCK / 4) + threadIdx.x;  // vec4 column index
    const ivec4* yv = y + (size_t)k0 * N4 + col4;

    int acc0 = 0, acc1 = 0, acc2 = 0, acc3 = 0;
    int sx = 0;

    // 16-deep unroll: 16 outstanding dwordx4 loads per lane (16 KiB in flight per wave).
#pragma unroll 16
    for (int k = 0; k < KCHUNK; ++k) {
        ivec4 v = __builtin_nontemporal_load(&yv[(size_t)k * N4]);
        int a = xs[k];
        sx   += a;
        acc0 += a * v.x;
        acc1 += a * v.y;
        acc2 += a * v.z;
        acc3 += a * v.w;
    }

    // Fold this chunk's zero-point correction into the partial -> reduce is a pure sum.
    const int corr = Y_ZP * sx;
    ivec4 p;
    p.x = acc0 - corr;
    p.y = acc1 - corr;
    p.z = acc2 - corr;
    p.w = acc3 - corr;
    ws[(size_t)kc * N4 + col4] = p;
}

__global__ __launch_bounds__(BLOCK) void qgemv_reduce(const ivec4* __restrict__ ws,
                                                      float* __restrict__ out) {
    const int t = blockIdx.x * BLOCK + threadIdx.x;  // 0 .. N4-1
    int sx = 0, sy = 0, sz = 0, sw = 0;
#pragma unroll 8
    for (int kc = 0; kc < SPLIT_K; ++kc) {
        ivec4 v = ws[(size_t)kc * N4 + t];
        sx += v.x; sy += v.y; sz += v.z; sw += v.w;
    }
    const float s = X_SCALE * Y_SCALE;
    float4 o;
    o.x = s * (float)sx;
    o.y = s * (float)sy;
    o.z = s * (float)sz;
    o.w = s * (float)sw;
    ((float4*)out)[t] = o;
}

extern "C" void kernel_launch(void* const* d_in, const int* in_sizes, int n_in,
                              void* d_out, int out_size, void* d_ws, size_t ws_size,
                              hipStream_t stream) {
    const int* x = (const int*)d_in[0];
    const ivec4* y = (const ivec4*)d_in[1];
    float* out = (float*)d_out;
    ivec4* ws = (ivec4*)d_ws;   // 64 x 4096 x 16 B = 4 MiB of the workspace

    qgemv_partial<<<NBLK_N * SPLIT_K, BLOCK, 0, stream>>>(x, y, ws);
    qgemv_reduce<<<N4 / BLOCK, BLOCK, 0, stream>>>(ws, out);
}